// Round 13
// baseline (168.500 us; speedup 1.0000x reference)
//
#include <hip/hip_runtime.h>
#include <hip/hip_bf16.h>
#include <math.h>

#define DIM   768
#define HID   128
#define H2    256
#define NENT  128
#define SPAN  16
#define NCLS  5

// ---- ws layout (bytes) ----
// poolB bf16 [3][128][256]              @ 0          (196,608)
// hepN  bf16 [beta 256][k 128][i 128]   @ 196608     (8,388,608)
// tepN  bf16 [b 256][k 128][j 128]      @ 8585216    (8,388,608)
// TclsB bf16 [m][c][b]                  @ 16973824   (655,360)
// WB    bf16 [3][768][768]              @ 17629184   (3,538,944)
// tokB  bf16 [3][2048][768]             @ 21168128   (9,437,184)   dead after gates
// gates fp32 [3][2048][768]             @ 30605312   (18,874,368)  dead after epilogue
// tmp30 bf16 [b][a][k] 256*256*128      @ 21168128   (16,777,216)  dead after gemm2
// tmp31 bf16 [b][a][k]                  @ 37945344   (16,777,216)  dead after gemm2
// predT fp32 [k*5+m][i][j]              @ 21168128   (41,943,040)  after gemm2
// max end = 63,111,168 B (ws >= 67.5 MB proven in round 1)
#define POOLB_OFF 0
#define HEPB_OFF  196608
#define TEPB_OFF  (HEPB_OFF + 8388608)
#define TCLSB_OFF (TEPB_OFF + 8388608)
#define WB_OFF    (TCLSB_OFF + 655360)
#define TOKB_OFF  21168128
#define GATES_OFF (TOKB_OFF + 9437184)
#define TMP30_OFF 21168128
#define TMP31_OFF (TMP30_OFF + 16777216)
#define PREDT_OFF 21168128

typedef __attribute__((ext_vector_type(8))) short bf16x8;
typedef __attribute__((ext_vector_type(4))) float f32x4;

__device__ __forceinline__ float sigmoidf_(float x) { return 1.0f / (1.0f + __expf(-x)); }

__device__ __forceinline__ unsigned short f2bf(float x) {
    __hip_bfloat16 h = __float2bfloat16(x);
    return *reinterpret_cast<unsigned short*>(&h);
}

// ---------------- prep: wconv + conv_tcls + gather_toks fused ----------------
__global__ __launch_bounds__(256)
void prep_kernel(const float* __restrict__ Whf, const float* __restrict__ Whb,
                 const float* __restrict__ Wtf, const float* __restrict__ Wtb,
                 const float* __restrict__ Wef, const float* __restrict__ Web,
                 const float* __restrict__ Tcls, const float* __restrict__ enc,
                 const int* __restrict__ idx_h, const int* __restrict__ idx_t,
                 const int* __restrict__ idx_e,
                 unsigned short* __restrict__ WB, unsigned short* __restrict__ TB,
                 unsigned short* __restrict__ tokB)
{
    const int bb = blockIdx.x;
    const int tid = threadIdx.x;
    if (bb < 1728) {
        int gid = bb * 256 + tid;                        // < 442368
        int t2  = gid / 73728;
        int rem = gid % 73728;
        int n   = rem / 192;
        int c4  = rem % 192;
        int gate = n >> 7, j = n & 127;
        int srow = (gate == 0) ? j : (gate == 1) ? 256 + j : 384 + j;
        const float* W = (t2 == 0) ? Whf : (t2 == 1) ? Whb : (t2 == 2) ? Wtf :
                         (t2 == 3) ? Wtb : (t2 == 4) ? Wef : Web;
        float4 v = ((const float4*)(W + srow * DIM))[c4];
        unsigned short* d = WB + ((size_t)(t2 * 384 + n)) * DIM + c4 * 4;
        d[0] = f2bf(v.x); d[1] = f2bf(v.y); d[2] = f2bf(v.z); d[3] = f2bf(v.w);
    } else if (bb < 3008) {
        int idx = (bb - 1728) * 256 + tid;               // < 327680
        int b = idx / (NCLS * H2);
        int r = idx % (NCLS * H2);
        int m = r >> 8, c = r & 255;
        TB[((m << 8) + c) * H2 + b] = f2bf(Tcls[idx]);
    } else {
        int gid = (bb - 3008) * 256 + tid;               // < 6144*192
        int r  = gid / 192, c4 = gid % 192;
        int type = r >> 11;
        int rem  = r & 2047;
        const int* idx = (type == 0) ? idx_h : (type == 1) ? idx_t : idx_e;
        int row = idx[rem];
        float4 v = ((const float4*)(enc + (size_t)row * DIM))[c4];
        unsigned short h4[4] = { f2bf(v.x), f2bf(v.y), f2bf(v.z), f2bf(v.w) };
        *(uint2*)(tokB + (size_t)r * DIM + c4 * 4) = *(uint2*)h4;
    }
}

// ---------------- gates GEMM (NT), LDS-staged 2-phase double-buffer ----------------
__global__ __launch_bounds__(256)
void gates_mfma(const unsigned short* __restrict__ tokB,
                const unsigned short* __restrict__ WB,
                float* __restrict__ gates)
{
    __shared__ unsigned short As[2][128 * 64];
    __shared__ unsigned short Bs[2][128 * 64];
    const int lbid = ((int)blockIdx.x & 7) * 36 + ((int)blockIdx.x >> 3);  // bijective
    const int type = lbid / 96;
    const int rem  = lbid % 96;
    const int mb0  = (rem / 6) * 128;
    const int nb0  = (rem % 6) * 128;
    const int tid = threadIdx.x;
    const int w = tid >> 6, l = tid & 63;
    const int lr = l & 15, lg = l >> 4;
    const unsigned short* A = tokB + (size_t)type * 2048 * DIM + (size_t)mb0 * DIM;
    const unsigned short* B = WB   + (size_t)type * 768  * DIM + (size_t)nb0 * DIM;

    const int sr0 = tid >> 3;
    const int sc  = tid & 7;

    bf16x8 ra[4], rb[4];
    #define LOADT(kt)                                                        \
        {                                                                    \
            const int koff = (kt) * 64 + sc * 8;                             \
            _Pragma("unroll")                                                \
            for (int p = 0; p < 4; ++p) {                                    \
                int rr = sr0 + p * 32;                                       \
                ra[p] = *(const bf16x8*)(A + (size_t)rr * DIM + koff);       \
                rb[p] = *(const bf16x8*)(B + (size_t)rr * DIM + koff);       \
            }                                                                \
        }
    #define WRITET(buf)                                                      \
        {                                                                    \
            _Pragma("unroll")                                                \
            for (int p = 0; p < 4; ++p) {                                    \
                int rr = sr0 + p * 32;                                       \
                int bo = (rr * 128 + sc * 16) ^ ((rr & 7) << 4);             \
                *(bf16x8*)((char*)As[buf] + bo) = ra[p];                     \
                *(bf16x8*)((char*)Bs[buf] + bo) = rb[p];                     \
            }                                                                \
        }

    f32x4 acc[4][4];
    #pragma unroll
    for (int mt = 0; mt < 4; ++mt)
        #pragma unroll
        for (int nt = 0; nt < 4; ++nt) acc[mt][nt] = (f32x4){0.f, 0.f, 0.f, 0.f};

    const int am0 = (w & 1) * 64;
    const int bn0 = (w >> 1) * 64;

    LOADT(0);
    WRITET(0);
    __syncthreads();

    int cur = 0;
    #pragma unroll 1
    for (int kt = 0; kt < 12; ++kt) {
        if (kt + 1 < 12) LOADT(kt + 1);

        #pragma unroll
        for (int ks = 0; ks < 2; ++ks) {
            bf16x8 af[4], bf[4];
            #pragma unroll
            for (int mt = 0; mt < 4; ++mt) {
                int rr = am0 + mt * 16 + lr;
                int bo = (rr * 128 + ks * 64 + lg * 16) ^ ((rr & 7) << 4);
                af[mt] = *(const bf16x8*)((const char*)As[cur] + bo);
            }
            #pragma unroll
            for (int nt = 0; nt < 4; ++nt) {
                int rr = bn0 + nt * 16 + lr;
                int bo = (rr * 128 + ks * 64 + lg * 16) ^ ((rr & 7) << 4);
                bf[nt] = *(const bf16x8*)((const char*)Bs[cur] + bo);
            }
            #pragma unroll
            for (int mt = 0; mt < 4; ++mt)
                #pragma unroll
                for (int nt = 0; nt < 4; ++nt)
                    acc[mt][nt] = __builtin_amdgcn_mfma_f32_16x16x32_bf16(af[mt], bf[nt], acc[mt][nt], 0, 0, 0);
        }

        if (kt + 1 < 12) {
            WRITET(cur ^ 1);
        }
        __syncthreads();
        cur ^= 1;
    }
    #undef LOADT
    #undef WRITET

    float* C = gates + (size_t)type * 2048 * 768 + (size_t)mb0 * 768 + nb0;
    #pragma unroll
    for (int mt = 0; mt < 4; ++mt)
        #pragma unroll
        for (int nt = 0; nt < 4; ++nt)
            #pragma unroll
            for (int r = 0; r < 4; ++r)
                C[(size_t)(am0 + mt * 16 + lg * 4 + r) * 768 + bn0 + nt * 16 + lr] = acc[mt][nt][r];
}

// ---------------- pool epilogue ----------------
__global__ __launch_bounds__(256)
void pool_epilogue(const float* __restrict__ gates,
                   const float* __restrict__ bhf, const float* __restrict__ bhb,
                   const float* __restrict__ btf, const float* __restrict__ btb,
                   const float* __restrict__ bef, const float* __restrict__ beb,
                   unsigned short* __restrict__ poolB)
{
    const int type = blockIdx.x >> 7;
    const int ent  = blockIdx.x & 127;
    const int tid  = threadIdx.x;
    const int dir  = tid >> 7;
    const int j    = tid & 127;
    const float* Bv = (type == 0) ? (dir ? bhb : bhf)
                    : (type == 1) ? (dir ? btb : btf)
                                  : (dir ? beb : bef);
    const float bi = Bv[j], bg = Bv[2 * HID + j], bo = Bv[3 * HID + j];
    const float* g0 = gates + ((size_t)type * 2048 + ent * 16) * 768 + dir * 384 + j;
    float hmax = -1e30f;
    #pragma unroll
    for (int l = 0; l < SPAN; ++l) {
        const float* gr = g0 + l * 768;
        float iv = sigmoidf_(gr[0]   + bi);
        float gv = tanhf(   gr[128] + bg);
        float ov = sigmoidf_(gr[256] + bo);
        hmax = fmaxf(hmax, ov * tanhf(iv * gv));
    }
    poolB[(size_t)(type * NENT + ent) * H2 + dir * HID + j] = f2bf(hmax);
}

// ---------------- gemm1: block (t, a) -- CONTIGUOUS 256KB T-slab read ----------------
// W[b][k] = sum_c T_t[a][b][c] * Ee[k][c]; store tmp3[t][b][a][k]
// grid 512; 1024 thr = 16 waves (bw 8 x kw 2, wave 32b x 64k). LDS 128 KB slab [256b][256c] swz.
__global__ __launch_bounds__(1024)
void gemm1_mfma(const unsigned short* __restrict__ EeB,
                const float* __restrict__ T0, const float* __restrict__ T1,
                unsigned short* __restrict__ tmp30, unsigned short* __restrict__ tmp31)
{
    __shared__ __align__(16) char smem[131072];
    const int bid = blockIdx.x;
    const int t = bid >> 8;
    const int a = bid & 255;
    const float* T = t ? T1 : T0;
    unsigned short* outp = t ? tmp31 : tmp30;
    const int tid = threadIdx.x;
    const int w = tid >> 6, l = tid & 63;
    const int lr = l & 15, lg = l >> 4;

    // ---- stage T[a][:][:] (256 KB fully contiguous; 2 KB per wave-instruction pair)
    {
        const int r0 = tid >> 5;
        const int ch = tid & 31;
        const float* base = T + (size_t)a * 65536;
        #pragma unroll
        for (int p = 0; p < 8; ++p) {
            int row = p * 32 + r0;                 // b
            const float* src = base + row * 256 + ch * 8;
            float4 v0 = ((const float4*)src)[0];
            float4 v1 = ((const float4*)src)[1];
            bf16x8 hv; unsigned short* hp = (unsigned short*)&hv;
            hp[0]=f2bf(v0.x); hp[1]=f2bf(v0.y); hp[2]=f2bf(v0.z); hp[3]=f2bf(v0.w);
            hp[4]=f2bf(v1.x); hp[5]=f2bf(v1.y); hp[6]=f2bf(v1.z); hp[7]=f2bf(v1.w);
            int bo = (row * 512 + ch * 16) ^ ((row & 7) << 4);
            *(bf16x8*)(smem + bo) = hv;
        }
    }
    __syncthreads();

    // ---- GEMM: M=256 b, N=128 k, K=256 c
    const int bw = (w & 7) * 32;
    const int kw = (w >> 3) * 64;
    f32x4 acc[2][4];
    #pragma unroll
    for (int mt = 0; mt < 2; ++mt)
        #pragma unroll
        for (int nt = 0; nt < 4; ++nt) acc[mt][nt] = (f32x4){0.f, 0.f, 0.f, 0.f};

    #pragma unroll
    for (int ks = 0; ks < 8; ++ks) {
        bf16x8 af[2], bf[4];
        #pragma unroll
        for (int mt = 0; mt < 2; ++mt) {
            int br = bw + mt * 16 + lr;
            int bo = (br * 512 + (ks * 32 + lg * 8) * 2) ^ ((br & 7) << 4);
            af[mt] = *(const bf16x8*)(smem + bo);
        }
        #pragma unroll
        for (int nt = 0; nt < 4; ++nt)
            bf[nt] = *(const bf16x8*)(EeB + (kw + nt * 16 + lr) * H2 + ks * 32 + lg * 8);
        #pragma unroll
        for (int mt = 0; mt < 2; ++mt)
            #pragma unroll
            for (int nt = 0; nt < 4; ++nt)
                acc[mt][nt] = __builtin_amdgcn_mfma_f32_16x16x32_bf16(af[mt], bf[nt], acc[mt][nt], 0, 0, 0);
    }

    // ---- write tmp3[b][a][k] (row=b from A-side, col=k from B-side)
    #pragma unroll
    for (int mt = 0; mt < 2; ++mt)
        #pragma unroll
        for (int nt = 0; nt < 4; ++nt)
            #pragma unroll
            for (int r = 0; r < 4; ++r) {
                int b_ = bw + mt * 16 + lg * 4 + r;
                int k_ = kw + nt * 16 + lr;
                outp[((size_t)b_ * 256 + a) * 128 + k_] = f2bf(acc[mt][nt][r]);
            }
}

// ---------------- gemm2: block (t, b) -- contiguous 64KB tmp3 read, transpose-stage ----
// out[b][k][i] = sum_a tmp3[b][a][k] * Hx[i][a]
// grid 512; 512 thr = 8 waves (kw 2 x iw 4, wave 64k x 32i). LDS 64 KB WT[128k][256a] swz.
__global__ __launch_bounds__(512)
void gemm2_mfma(const unsigned short* __restrict__ HeB, const unsigned short* __restrict__ TeB,
                const unsigned short* __restrict__ tmp30, const unsigned short* __restrict__ tmp31,
                unsigned short* __restrict__ hepN, unsigned short* __restrict__ tepN)
{
    __shared__ unsigned short WT[128 * 256];
    const int bid = blockIdx.x;
    const int t = bid >> 8;
    const int b = bid & 255;
    const unsigned short* src = (t ? tmp31 : tmp30) + (size_t)b * 32768;
    const unsigned short* Hx = t ? TeB : HeB;
    unsigned short* outp = (t ? tepN : hepN) + (size_t)b * 16384;
    const int tid = threadIdx.x;
    const int w = tid >> 6, l = tid & 63;
    const int lr = l & 15, lg = l >> 4;

    // ---- transpose-stage [256a][128k] -> WT[k][a] swz (1KB contiguous reads per wave)
    {
        const int a0 = tid >> 4;
        const int k8 = (tid & 15) * 8;
        #pragma unroll
        for (int it = 0; it < 8; ++it) {
            int aa = it * 32 + a0;
            bf16x8 v = *(const bf16x8*)(src + aa * 128 + k8);
            #pragma unroll
            for (int j = 0; j < 8; ++j) {
                int kk = k8 + j;                       // kk&7 == j
                int bo = (kk * 512 + aa * 2) ^ (j << 4);
                *(unsigned short*)((char*)WT + bo) = ((unsigned short*)&v)[j];
            }
        }
    }
    __syncthreads();

    // ---- GEMM: M=128 k, N=128 i, K=256 a
    const int kw = (w & 1) * 64;
    const int iw = (w >> 1) * 32;
    f32x4 acc[4][2];
    #pragma unroll
    for (int mt = 0; mt < 4; ++mt)
        #pragma unroll
        for (int nt = 0; nt < 2; ++nt) acc[mt][nt] = (f32x4){0.f, 0.f, 0.f, 0.f};

    #pragma unroll
    for (int ks = 0; ks < 8; ++ks) {
        bf16x8 af[4], bf[2];
        #pragma unroll
        for (int mt = 0; mt < 4; ++mt) {
            int kr = kw + mt * 16 + lr;
            int bo = (kr * 512 + (ks * 32 + lg * 8) * 2) ^ ((kr & 7) << 4);
            af[mt] = *(const bf16x8*)((const char*)WT + bo);
        }
        #pragma unroll
        for (int nt = 0; nt < 2; ++nt)
            bf[nt] = *(const bf16x8*)(Hx + (iw + nt * 16 + lr) * H2 + ks * 32 + lg * 8);
        #pragma unroll
        for (int mt = 0; mt < 4; ++mt)
            #pragma unroll
            for (int nt = 0; nt < 2; ++nt)
                acc[mt][nt] = __builtin_amdgcn_mfma_f32_16x16x32_bf16(af[mt], bf[nt], acc[mt][nt], 0, 0, 0);
    }
    #pragma unroll
    for (int mt = 0; mt < 4; ++mt)
        #pragma unroll
        for (int nt = 0; nt < 2; ++nt)
            #pragma unroll
            for (int r = 0; r < 4; ++r) {
                int k_ = kw + mt * 16 + lg * 4 + r;
                int i_ = iw + nt * 16 + lr;
                outp[k_ * 128 + i_] = f2bf(acc[mt][nt][r]);
            }
}

// ---------------- step3: block per (k, j-half); m-loop inside ----------------
__global__ __launch_bounds__(512)
void step3_mfma(const unsigned short* __restrict__ hepN,  // [256 beta][128 k][128 i]
                const unsigned short* __restrict__ tepN,  // [256 b][128 k][128 j]
                const unsigned short* __restrict__ TclsB, // [m][c][b]
                float* __restrict__ predT)
{
    __shared__ unsigned short hepS[128 * 256];  // [i][beta] swz, 64 KB
    __shared__ unsigned short tepS[64 * 256];   // [j][b] swz, 32 KB
    __shared__ unsigned short WS[64 * 256];     // [j][c] swz, 32 KB
    const int lbid = (blockIdx.x & 7) * 32 + (blockIdx.x >> 3);
    const int k  = lbid >> 1;
    const int jh = lbid & 1;
    const int tid = threadIdx.x;
    const int w  = tid >> 6;
    const int l  = tid & 63;
    const int lr = l & 15;
    const int lg = l >> 4;
    const int swz = (lr & 7) << 4;

    #pragma unroll
    for (int q = 0; q < 4; ++q) {
        int bcol = q * 64 + l;
        bf16x8 v = *(const bf16x8*)(tepN + ((size_t)bcol * 128 + k) * 128 + jh * 64 + w * 8);
        #pragma unroll
        for (int r = 0; r < 8; ++r) {
            int j = w * 8 + r;
            int bo = (j * 512 + bcol * 2) ^ (r << 4);
            *(unsigned short*)((char*)tepS + bo) = ((unsigned short*)&v)[r];
        }
    }
    #pragma unroll
    for (int s = 0; s < 2; ++s)
        #pragma unroll
        for (int q = 0; q < 4; ++q) {
            int bcol = q * 64 + l;
            bf16x8 v = *(const bf16x8*)(hepN + ((size_t)bcol * 128 + k) * 128 + w * 16 + s * 8);
            #pragma unroll
            for (int r = 0; r < 8; ++r) {
                int i = w * 16 + s * 8 + r;
                int bo = (i * 512 + bcol * 2) ^ (r << 4);
                *(unsigned short*)((char*)hepS + bo) = ((unsigned short*)&v)[r];
            }
        }
    __syncthreads();

    bf16x8 ha[8];
    #pragma unroll
    for (int ks = 0; ks < 8; ++ks) {
        int ir = w * 16 + lr;
        int bo = (ir * 512 + (ks * 32 + lg * 8) * 2) ^ ((ir & 7) << 4);
        ha[ks] = *(const bf16x8*)((const char*)hepS + bo);
    }

    #pragma unroll 1
    for (int m = 0; m < NCLS; ++m) {
        {
            const unsigned short* tcm = TclsB + (size_t)m * (H2 * H2);
            f32x4 acc1[4][2];
            #pragma unroll
            for (int jt = 0; jt < 4; ++jt)
                #pragma unroll
                for (int ct = 0; ct < 2; ++ct) acc1[jt][ct] = (f32x4){0.f, 0.f, 0.f, 0.f};

            #pragma unroll
            for (int ks = 0; ks < 8; ++ks) {
                bf16x8 a[4], bb[2];
                #pragma unroll
                for (int jt = 0; jt < 4; ++jt) {
                    int byteoff = ((((jt * 16 + lr) << 8) + ks * 32 + lg * 8) << 1) ^ swz;
                    a[jt] = *(const bf16x8*)((const char*)tepS + byteoff);
                }
                #pragma unroll
                for (int ct = 0; ct < 2; ++ct)
                    bb[ct] = *(const bf16x8*)(tcm + (size_t)(w * 32 + ct * 16 + lr) * H2 + ks * 32 + lg * 8);
                #pragma unroll
                for (int jt = 0; jt < 4; ++jt)
                    #pragma unroll
                    for (int ct = 0; ct < 2; ++ct)
                        acc1[jt][ct] = __builtin_amdgcn_mfma_f32_16x16x32_bf16(a[jt], bb[ct], acc1[jt][ct], 0, 0, 0);
            }
            #pragma unroll
            for (int jt = 0; jt < 4; ++jt)
                #pragma unroll
                for (int ct = 0; ct < 2; ++ct)
                    #pragma unroll
                    for (int r = 0; r < 4; ++r) {
                        int j = jt * 16 + lg * 4 + r;
                        int c = w * 32 + ct * 16 + lr;
                        int byteoff = ((((j << 8) + c)) << 1) ^ ((j & 7) << 4);
                        *(unsigned short*)((char*)WS + byteoff) = f2bf(acc1[jt][ct][r]);
                    }
        }
        __syncthreads();

        {
            f32x4 acc2[4];
            #pragma unroll
            for (int jt = 0; jt < 4; ++jt) acc2[jt] = (f32x4){0.f, 0.f, 0.f, 0.f};

            #pragma unroll
            for (int ks = 0; ks < 8; ++ks) {
                #pragma unroll
                for (int jt = 0; jt < 4; ++jt) {
                    int byteoff = ((((jt * 16 + lr) << 8) + ks * 32 + lg * 8) << 1) ^ swz;
                    bf16x8 wb = *(const bf16x8*)((const char*)WS + byteoff);
                    acc2[jt] = __builtin_amdgcn_mfma_f32_16x16x32_bf16(ha[ks], wb, acc2[jt], 0, 0, 0);
                }
            }
            float* po = predT + (size_t)(k * NCLS + m) * (NENT * NENT);
            #pragma unroll
            for (int jt = 0; jt < 4; ++jt)
                #pragma unroll
                for (int r = 0; r < 4; ++r) {
                    int i = w * 16 + lg * 4 + r;
                    int j = jh * 64 + jt * 16 + lr;
                    po[i * NENT + j] = acc2[jt][r];
                }
        }
        __syncthreads();
    }
}

// ---------------- transpose: predT[km][ij] -> out[ij][km] ----------------
__global__ __launch_bounds__(256)
void transpose_out(const float* __restrict__ predT, float* __restrict__ out)
{
    __shared__ float Ls[160][33];
    const int bid = blockIdx.x;
    const int ij0 = (bid >> 2) * 32;
    const int km0 = (bid & 3) * 160;
    const int t = threadIdx.x;

    #pragma unroll
    for (int q = 0; q < 20; ++q) {
        int r = (t >> 5) + q * 8;
        int c = t & 31;
        Ls[r][c] = predT[(size_t)(km0 + r) * 16384 + ij0 + c];
    }
    __syncthreads();
    for (int idx = t; idx < 32 * 160; idx += 256) {
        int r = idx / 160, c = idx % 160;
        out[(size_t)(ij0 + r) * 640 + km0 + c] = Ls[c][r];
    }
}

extern "C" void kernel_launch(void* const* d_in, const int* in_sizes, int n_in,
                              void* d_out, int out_size, void* d_ws, size_t ws_size,
                              hipStream_t stream)
{
    (void)in_sizes; (void)n_in; (void)out_size; (void)ws_size;
    const float* enc  = (const float*)d_in[0];
    const int*   hidx = (const int*)d_in[1];
    const int*   tidx = (const int*)d_in[2];
    const int*   eidx = (const int*)d_in[3];
    const float* Whf = (const float*)d_in[4];
    const float* bhf = (const float*)d_in[5];
    const float* Whb = (const float*)d_in[6];
    const float* bhb = (const float*)d_in[7];
    const float* Wtf = (const float*)d_in[8];
    const float* btf = (const float*)d_in[9];
    const float* Wtb = (const float*)d_in[10];
    const float* btb = (const float*)d_in[11];
    const float* Wef = (const float*)d_in[12];
    const float* bef = (const float*)d_in[13];
    const float* Web = (const float*)d_in[14];
    const float* beb = (const float*)d_in[15];
    const float* T_he  = (const float*)d_in[16];
    const float* T_te  = (const float*)d_in[17];
    const float* T_cls = (const float*)d_in[18];

    float* out = (float*)d_out;
    char*  ws  = (char*)d_ws;
    unsigned short* poolB = (unsigned short*)(ws + POOLB_OFF);
    unsigned short* hepN  = (unsigned short*)(ws + HEPB_OFF);
    unsigned short* tepN  = (unsigned short*)(ws + TEPB_OFF);
    unsigned short* TclsB = (unsigned short*)(ws + TCLSB_OFF);
    unsigned short* WB    = (unsigned short*)(ws + WB_OFF);
    unsigned short* tokB  = (unsigned short*)(ws + TOKB_OFF);
    float*          gates = (float*)(ws + GATES_OFF);
    unsigned short* tmp30 = (unsigned short*)(ws + TMP30_OFF);
    unsigned short* tmp31 = (unsigned short*)(ws + TMP31_OFF);
    float*          predT = (float*)(ws + PREDT_OFF);

    unsigned short* HeB = poolB;
    unsigned short* TeB = poolB + 1 * NENT * H2;
    unsigned short* EeB = poolB + 2 * NENT * H2;

    prep_kernel<<<7616, 256, 0, stream>>>(Whf, Whb, Wtf, Wtb, Wef, Web,
                                          T_cls, enc, hidx, tidx, eidx,
                                          WB, TclsB, tokB);

    gates_mfma<<<288, 256, 0, stream>>>(tokB, WB, gates);

    pool_epilogue<<<384, 256, 0, stream>>>(gates, bhf, bhb, btf, btb, bef, beb, poolB);

    gemm1_mfma<<<512, 1024, 0, stream>>>(EeB, T_he, T_te, tmp30, tmp31);

    gemm2_mfma<<<512, 512, 0, stream>>>(HeB, TeB, tmp30, tmp31, hepN, tepN);

    step3_mfma<<<256, 512, 0, stream>>>(hepN, tepN, TclsB, predT);

    transpose_out<<<2048, 256, 0, stream>>>(predT, out);
}

// Round 14
// 140.896 us; speedup vs baseline: 1.1959x; 1.1959x over previous
//
#include <hip/hip_runtime.h>
#include <hip/hip_bf16.h>
#include <math.h>

#define DIM   768
#define HID   128
#define H2    256
#define NENT  128
#define SPAN  16
#define NCLS  5

// ---- ws layout (bytes) ----
// poolB  bf16 [3][128][256]             @ 0          (196,608)    K3-K4
// hepN   bf16 [beta][k][i]              @ 196608     (8,388,608)  K4-K5
// tepN   bf16 [b][k][j]                 @ 8585216    (8,388,608)  K4-K5
// TclsB  bf16 [m][c][b]                 @ 16973824   (655,360)    K1-K5
// WB     bf16 [3][768][768]             @ 17629184   (3,538,944)  K1-K2 (dead after gates)
// tokB   bf16 [3][2048][768]            @ 21168128   (9,437,184)  K1-K2 (dead after gates)
// TB     bf16 [b][a][c] (T_he)          @ 21168128   (33,554,432) K3-K4 (overlaps tokB: dead)
// gatesB bf16 [3][2048][768]            @ 58060800   (9,437,184)  K2-K3
// predT  fp32 [k*5+m][i][j]             @ 21168128   (41,943,040) K5-K6 (overlaps TB: dead)
// peak = 67,497,984 B <= 67,502,080 proven (round-1 map)
#define POOLB_OFF  0
#define HEPB_OFF   196608
#define TEPB_OFF   (HEPB_OFF + 8388608)
#define TCLSB_OFF  (TEPB_OFF + 8388608)
#define WB_OFF     (TCLSB_OFF + 655360)
#define TOKB_OFF   21168128
#define TB_OFF     21168128
#define GATESB_OFF 58060800
#define PREDT_OFF  21168128

typedef __attribute__((ext_vector_type(8))) short bf16x8;
typedef __attribute__((ext_vector_type(4))) float f32x4;

__device__ __forceinline__ float sigmoidf_(float x) { return 1.0f / (1.0f + __expf(-x)); }

__device__ __forceinline__ unsigned short f2bf(float x) {
    __hip_bfloat16 h = __float2bfloat16(x);
    return *reinterpret_cast<unsigned short*>(&h);
}
__device__ __forceinline__ float bf2f(unsigned short u) {
    unsigned int v = ((unsigned int)u) << 16;
    float f; __builtin_memcpy(&f, &v, 4); return f;
}

// ---------------- prep: wconv + conv_tcls + gather_toks fused ----------------
__global__ __launch_bounds__(256)
void prep_kernel(const float* __restrict__ Whf, const float* __restrict__ Whb,
                 const float* __restrict__ Wtf, const float* __restrict__ Wtb,
                 const float* __restrict__ Wef, const float* __restrict__ Web,
                 const float* __restrict__ Tcls, const float* __restrict__ enc,
                 const int* __restrict__ idx_h, const int* __restrict__ idx_t,
                 const int* __restrict__ idx_e,
                 unsigned short* __restrict__ WB, unsigned short* __restrict__ TB,
                 unsigned short* __restrict__ tokB)
{
    const int bb = blockIdx.x;
    const int tid = threadIdx.x;
    if (bb < 1728) {
        int gid = bb * 256 + tid;                        // < 442368
        int t2  = gid / 73728;
        int rem = gid % 73728;
        int n   = rem / 192;
        int c4  = rem % 192;
        int gate = n >> 7, j = n & 127;
        int srow = (gate == 0) ? j : (gate == 1) ? 256 + j : 384 + j;
        const float* W = (t2 == 0) ? Whf : (t2 == 1) ? Whb : (t2 == 2) ? Wtf :
                         (t2 == 3) ? Wtb : (t2 == 4) ? Wef : Web;
        float4 v = ((const float4*)(W + srow * DIM))[c4];
        unsigned short* d = WB + ((size_t)(t2 * 384 + n)) * DIM + c4 * 4;
        d[0] = f2bf(v.x); d[1] = f2bf(v.y); d[2] = f2bf(v.z); d[3] = f2bf(v.w);
    } else if (bb < 3008) {
        int idx = (bb - 1728) * 256 + tid;               // < 327680
        int b = idx / (NCLS * H2);
        int r = idx % (NCLS * H2);
        int m = r >> 8, c = r & 255;
        TB[((m << 8) + c) * H2 + b] = f2bf(Tcls[idx]);
    } else {
        int gid = (bb - 3008) * 256 + tid;               // < 6144*192
        int r  = gid / 192, c4 = gid % 192;
        int type = r >> 11;
        int rem  = r & 2047;
        const int* idx = (type == 0) ? idx_h : (type == 1) ? idx_t : idx_e;
        int row = idx[rem];
        float4 v = ((const float4*)(enc + (size_t)row * DIM))[c4];
        unsigned short h4[4] = { f2bf(v.x), f2bf(v.y), f2bf(v.z), f2bf(v.w) };
        *(uint2*)(tokB + (size_t)r * DIM + c4 * 4) = *(uint2*)h4;
    }
}

// ---------------- gates GEMM (NT), LDS-staged 2-phase double-buffer; bf16 out ----------------
__global__ __launch_bounds__(256)
void gates_mfma(const unsigned short* __restrict__ tokB,
                const unsigned short* __restrict__ WB,
                unsigned short* __restrict__ gatesB)
{
    __shared__ unsigned short As[2][128 * 64];
    __shared__ unsigned short Bs[2][128 * 64];
    const int lbid = ((int)blockIdx.x & 7) * 36 + ((int)blockIdx.x >> 3);  // bijective
    const int type = lbid / 96;
    const int rem  = lbid % 96;
    const int mb0  = (rem / 6) * 128;
    const int nb0  = (rem % 6) * 128;
    const int tid = threadIdx.x;
    const int w = tid >> 6, l = tid & 63;
    const int lr = l & 15, lg = l >> 4;
    const unsigned short* A = tokB + (size_t)type * 2048 * DIM + (size_t)mb0 * DIM;
    const unsigned short* B = WB   + (size_t)type * 768  * DIM + (size_t)nb0 * DIM;

    const int sr0 = tid >> 3;
    const int sc  = tid & 7;

    bf16x8 ra[4], rb[4];
    #define LOADT(kt)                                                        \
        {                                                                    \
            const int koff = (kt) * 64 + sc * 8;                             \
            _Pragma("unroll")                                                \
            for (int p = 0; p < 4; ++p) {                                    \
                int rr = sr0 + p * 32;                                       \
                ra[p] = *(const bf16x8*)(A + (size_t)rr * DIM + koff);       \
                rb[p] = *(const bf16x8*)(B + (size_t)rr * DIM + koff);       \
            }                                                                \
        }
    #define WRITET(buf)                                                      \
        {                                                                    \
            _Pragma("unroll")                                                \
            for (int p = 0; p < 4; ++p) {                                    \
                int rr = sr0 + p * 32;                                       \
                int bo = (rr * 128 + sc * 16) ^ ((rr & 7) << 4);             \
                *(bf16x8*)((char*)As[buf] + bo) = ra[p];                     \
                *(bf16x8*)((char*)Bs[buf] + bo) = rb[p];                     \
            }                                                                \
        }

    f32x4 acc[4][4];
    #pragma unroll
    for (int mt = 0; mt < 4; ++mt)
        #pragma unroll
        for (int nt = 0; nt < 4; ++nt) acc[mt][nt] = (f32x4){0.f, 0.f, 0.f, 0.f};

    const int am0 = (w & 1) * 64;
    const int bn0 = (w >> 1) * 64;

    LOADT(0);
    WRITET(0);
    __syncthreads();

    int cur = 0;
    #pragma unroll 1
    for (int kt = 0; kt < 12; ++kt) {
        if (kt + 1 < 12) LOADT(kt + 1);

        #pragma unroll
        for (int ks = 0; ks < 2; ++ks) {
            bf16x8 af[4], bf[4];
            #pragma unroll
            for (int mt = 0; mt < 4; ++mt) {
                int rr = am0 + mt * 16 + lr;
                int bo = (rr * 128 + ks * 64 + lg * 16) ^ ((rr & 7) << 4);
                af[mt] = *(const bf16x8*)((const char*)As[cur] + bo);
            }
            #pragma unroll
            for (int nt = 0; nt < 4; ++nt) {
                int rr = bn0 + nt * 16 + lr;
                int bo = (rr * 128 + ks * 64 + lg * 16) ^ ((rr & 7) << 4);
                bf[nt] = *(const bf16x8*)((const char*)Bs[cur] + bo);
            }
            #pragma unroll
            for (int mt = 0; mt < 4; ++mt)
                #pragma unroll
                for (int nt = 0; nt < 4; ++nt)
                    acc[mt][nt] = __builtin_amdgcn_mfma_f32_16x16x32_bf16(af[mt], bf[nt], acc[mt][nt], 0, 0, 0);
        }

        if (kt + 1 < 12) {
            WRITET(cur ^ 1);
        }
        __syncthreads();
        cur ^= 1;
    }
    #undef LOADT
    #undef WRITET

    unsigned short* C = gatesB + (size_t)type * 2048 * 768 + (size_t)mb0 * 768 + nb0;
    #pragma unroll
    for (int mt = 0; mt < 4; ++mt)
        #pragma unroll
        for (int nt = 0; nt < 4; ++nt)
            #pragma unroll
            for (int r = 0; r < 4; ++r)
                C[(size_t)(am0 + mt * 16 + lg * 4 + r) * 768 + bn0 + nt * 16 + lr] = f2bf(acc[mt][nt][r]);
}

// ---------------- poolconv: pool epilogue (384 blocks) U convT T_he->TB (512 blocks) ------
// convT: perfectly-sequential grid-stride stream, fp32 -> bf16, TB[b][a][c].
__global__ __launch_bounds__(256)
void poolconv(const unsigned short* __restrict__ gatesB,
              const float* __restrict__ bhf, const float* __restrict__ bhb,
              const float* __restrict__ btf, const float* __restrict__ btb,
              const float* __restrict__ bef, const float* __restrict__ beb,
              unsigned short* __restrict__ poolB,
              const float* __restrict__ T0, unsigned short* __restrict__ TB)
{
    const int bb = blockIdx.x;
    const int tid = threadIdx.x;
    if (bb < 384) {
        const int type = bb >> 7;
        const int ent  = bb & 127;
        const int dir  = tid >> 7;
        const int j    = tid & 127;
        const float* Bv = (type == 0) ? (dir ? bhb : bhf)
                        : (type == 1) ? (dir ? btb : btf)
                                      : (dir ? beb : bef);
        const float bi = Bv[j], bg = Bv[2 * HID + j], bo = Bv[3 * HID + j];
        const unsigned short* g0 = gatesB + ((size_t)type * 2048 + ent * 16) * 768 + dir * 384 + j;
        float hmax = -1e30f;
        #pragma unroll
        for (int ll = 0; ll < SPAN; ++ll) {
            const unsigned short* gr = g0 + ll * 768;
            float iv = sigmoidf_(bf2f(gr[0])   + bi);
            float gv = tanhf(   bf2f(gr[128]) + bg);
            float ov = sigmoidf_(bf2f(gr[256]) + bo);
            hmax = fmaxf(hmax, ov * tanhf(iv * gv));
        }
        poolB[(size_t)(type * NENT + ent) * H2 + dir * HID + j] = f2bf(hmax);
    } else {
        // convT: 2,097,152 units of 32B fp32 -> 16B bf16
        int W0 = (bb - 384) * 256 + tid;                 // < 131072
        #pragma unroll 1
        for (int it = 0; it < 16; ++it) {
            int idx = W0 + it * 131072;
            int a  = idx >> 13;
            int rr = idx & 8191;
            int b  = rr >> 5;
            int c8 = rr & 31;
            const float* src = T0 + ((size_t)(a * 256 + b) << 8) + c8 * 8;
            float4 v0 = ((const float4*)src)[0];
            float4 v1 = ((const float4*)src)[1];
            bf16x8 hv; unsigned short* hp = (unsigned short*)&hv;
            hp[0]=f2bf(v0.x); hp[1]=f2bf(v0.y); hp[2]=f2bf(v0.z); hp[3]=f2bf(v0.w);
            hp[4]=f2bf(v1.x); hp[5]=f2bf(v1.y); hp[6]=f2bf(v1.z); hp[7]=f2bf(v1.w);
            *(bf16x8*)(TB + (((size_t)(b * 256 + a)) << 8) + c8 * 8) = hv;
        }
    }
}

// ---------------- pairc: fused W+out; t=0 stages from ws TB (bf16), t=1 from d_in T_te ----
// LDS slab: 4 panels [cs][256 a][128 B] bf16 (gates-shape rows -> conflict-free);
// WT aliases smem[0:64K] as 4 panels [as][128 k][128 B].
__global__ __launch_bounds__(1024)
void pairc_mfma(const unsigned short* __restrict__ EeB,
                const unsigned short* __restrict__ HeB,
                const unsigned short* __restrict__ TeB,
                const unsigned short* __restrict__ TB,  // [b][a][c] bf16 (T_he)
                const float* __restrict__ T1,           // T_te fp32 [a][b][c]
                unsigned short* __restrict__ hepN, unsigned short* __restrict__ tepN)
{
    __shared__ __align__(16) char smem[131072];
    const int bid = blockIdx.x;
    const int t = bid >> 8;
    const int b = bid & 255;
    const unsigned short* Hx = t ? TeB : HeB;
    unsigned short* outp = t ? tepN : hepN;
    const int tid = threadIdx.x;
    const int w = tid >> 6, l = tid & 63;
    const int lr = l & 15, lg = l >> 4;

    // ---- stage slab: chunk L = a*32 + ch (16B) -> panel ch>>3, row a, col (ch&7)*16, XOR (a&7)<<4
    if (t == 0) {
        const unsigned short* TBb = TB + (size_t)b * 65536;
        #pragma unroll
        for (int p = 0; p < 8; ++p) {
            int L = tid + p * 1024;
            int row = L >> 5, ch = L & 31;
            bf16x8 v = *(const bf16x8*)(TBb + (size_t)L * 8);
            int bo = (((ch >> 3) << 15) + row * 128 + ((ch & 7) << 4)) ^ ((row & 7) << 4);
            *(bf16x8*)(smem + bo) = v;
        }
    } else {
        #pragma unroll
        for (int p = 0; p < 8; ++p) {
            int L = tid + p * 1024;
            int row = L >> 5, ch = L & 31;
            const float* src = T1 + ((size_t)row * 256 + b) * 256 + ch * 8;
            float4 v0 = ((const float4*)src)[0];
            float4 v1 = ((const float4*)src)[1];
            bf16x8 hv; unsigned short* hp = (unsigned short*)&hv;
            hp[0]=f2bf(v0.x); hp[1]=f2bf(v0.y); hp[2]=f2bf(v0.z); hp[3]=f2bf(v0.w);
            hp[4]=f2bf(v1.x); hp[5]=f2bf(v1.y); hp[6]=f2bf(v1.z); hp[7]=f2bf(v1.w);
            int bo = (((ch >> 3) << 15) + row * 128 + ((ch & 7) << 4)) ^ ((row & 7) << 4);
            *(bf16x8*)(smem + bo) = hv;
        }
    }
    __syncthreads();

    // ---- P1: W[a][k] = sum_c slab[a][c] * Ee[k][c]; 16 waves: aw(4)x kw(4, 32k each)
    f32x4 acc1[4][2];
    const int aw = (w & 3) * 64;
    const int kw = (w >> 2) * 32;
    #pragma unroll
    for (int mt = 0; mt < 4; ++mt)
        #pragma unroll
        for (int nt = 0; nt < 2; ++nt) acc1[mt][nt] = (f32x4){0.f, 0.f, 0.f, 0.f};

    #pragma unroll
    for (int ks = 0; ks < 8; ++ks) {
        const int cb = ks * 64 + lg * 16;      // byte offset of c within 512B row
        bf16x8 af[4], bf[2];
        #pragma unroll
        for (int mt = 0; mt < 4; ++mt) {
            int a = aw + mt * 16 + lr;
            int bo = (((cb >> 7) << 15) + a * 128 + (cb & 127)) ^ ((a & 7) << 4);
            af[mt] = *(const bf16x8*)(smem + bo);
        }
        #pragma unroll
        for (int nt = 0; nt < 2; ++nt)
            bf[nt] = *(const bf16x8*)(EeB + (kw + nt * 16 + lr) * H2 + ks * 32 + lg * 8);
        #pragma unroll
        for (int mt = 0; mt < 4; ++mt)
            #pragma unroll
            for (int nt = 0; nt < 2; ++nt)
                acc1[mt][nt] = __builtin_amdgcn_mfma_f32_16x16x32_bf16(af[mt], bf[nt], acc1[mt][nt], 0, 0, 0);
    }
    __syncthreads();   // slab fully consumed

    // ---- WT write into smem[0:64K]: 4 panels [as][128 k][128 B]
    #pragma unroll
    for (int mt = 0; mt < 4; ++mt)
        #pragma unroll
        for (int nt = 0; nt < 2; ++nt) {
            int k  = kw + nt * 16 + lr;
            int a0 = aw + mt * 16 + lg * 4;
            unsigned short h4[4] = { f2bf(acc1[mt][nt][0]), f2bf(acc1[mt][nt][1]),
                                     f2bf(acc1[mt][nt][2]), f2bf(acc1[mt][nt][3]) };
            int bo = (((a0 >> 6) << 14) + k * 128 + ((a0 & 63) << 1)) ^ ((k & 7) << 4);
            *(uint2*)(smem + bo) = *(uint2*)h4;
        }
    __syncthreads();

    // ---- P2: out[b][k][i] = sum_a WT[k][a] * Hx[i][a]; 16 waves: kw2(2)x iw(8)
    {
        const int kw2 = (w >> 3) * 64;
        const int iw  = (w & 7) * 16;
        f32x4 acc2[4];
        #pragma unroll
        for (int mt = 0; mt < 4; ++mt) acc2[mt] = (f32x4){0.f, 0.f, 0.f, 0.f};

        #pragma unroll
        for (int ks = 0; ks < 8; ++ks) {
            const int ab = ks * 64 + lg * 16;
            bf16x8 af[4], bf;
            #pragma unroll
            for (int mt = 0; mt < 4; ++mt) {
                int k = kw2 + mt * 16 + lr;
                int bo = (((ab >> 7) << 14) + k * 128 + (ab & 127)) ^ ((k & 7) << 4);
                af[mt] = *(const bf16x8*)(smem + bo);
            }
            bf = *(const bf16x8*)(Hx + (iw + lr) * H2 + ks * 32 + lg * 8);
            #pragma unroll
            for (int mt = 0; mt < 4; ++mt)
                acc2[mt] = __builtin_amdgcn_mfma_f32_16x16x32_bf16(af[mt], bf, acc2[mt], 0, 0, 0);
        }
        unsigned short* po = outp + (size_t)b * (128 * 128);
        #pragma unroll
        for (int mt = 0; mt < 4; ++mt)
            #pragma unroll
            for (int r = 0; r < 4; ++r) {
                int k = kw2 + mt * 16 + lg * 4 + r;
                int i = iw + lr;
                po[k * 128 + i] = f2bf(acc2[mt][r]);
            }
    }
}

// ---------------- step3: block per (k, j-half); m-loop inside ----------------
__global__ __launch_bounds__(512)
void step3_mfma(const unsigned short* __restrict__ hepN,  // [256 beta][128 k][128 i]
                const unsigned short* __restrict__ tepN,  // [256 b][128 k][128 j]
                const unsigned short* __restrict__ TclsB, // [m][c][b]
                float* __restrict__ predT)
{
    __shared__ unsigned short hepS[128 * 256];
    __shared__ unsigned short tepS[64 * 256];
    __shared__ unsigned short WS[64 * 256];
    const int lbid = (blockIdx.x & 7) * 32 + (blockIdx.x >> 3);
    const int k  = lbid >> 1;
    const int jh = lbid & 1;
    const int tid = threadIdx.x;
    const int w  = tid >> 6;
    const int l  = tid & 63;
    const int lr = l & 15;
    const int lg = l >> 4;
    const int swz = (lr & 7) << 4;

    #pragma unroll
    for (int q = 0; q < 4; ++q) {
        int bcol = q * 64 + l;
        bf16x8 v = *(const bf16x8*)(tepN + ((size_t)bcol * 128 + k) * 128 + jh * 64 + w * 8);
        #pragma unroll
        for (int r = 0; r < 8; ++r) {
            int j = w * 8 + r;
            int bo = (j * 512 + bcol * 2) ^ (r << 4);
            *(unsigned short*)((char*)tepS + bo) = ((unsigned short*)&v)[r];
        }
    }
    #pragma unroll
    for (int s = 0; s < 2; ++s)
        #pragma unroll
        for (int q = 0; q < 4; ++q) {
            int bcol = q * 64 + l;
            bf16x8 v = *(const bf16x8*)(hepN + ((size_t)bcol * 128 + k) * 128 + w * 16 + s * 8);
            #pragma unroll
            for (int r = 0; r < 8; ++r) {
                int i = w * 16 + s * 8 + r;
                int bo = (i * 512 + bcol * 2) ^ (r << 4);
                *(unsigned short*)((char*)hepS + bo) = ((unsigned short*)&v)[r];
            }
        }
    __syncthreads();

    bf16x8 ha[8];
    #pragma unroll
    for (int ks = 0; ks < 8; ++ks) {
        int ir = w * 16 + lr;
        int bo = (ir * 512 + (ks * 32 + lg * 8) * 2) ^ ((ir & 7) << 4);
        ha[ks] = *(const bf16x8*)((const char*)hepS + bo);
    }

    #pragma unroll 1
    for (int m = 0; m < NCLS; ++m) {
        {
            const unsigned short* tcm = TclsB + (size_t)m * (H2 * H2);
            f32x4 acc1[4][2];
            #pragma unroll
            for (int jt = 0; jt < 4; ++jt)
                #pragma unroll
                for (int ct = 0; ct < 2; ++ct) acc1[jt][ct] = (f32x4){0.f, 0.f, 0.f, 0.f};

            #pragma unroll
            for (int ks = 0; ks < 8; ++ks) {
                bf16x8 a[4], bb[2];
                #pragma unroll
                for (int jt = 0; jt < 4; ++jt) {
                    int byteoff = ((((jt * 16 + lr) << 8) + ks * 32 + lg * 8) << 1) ^ swz;
                    a[jt] = *(const bf16x8*)((const char*)tepS + byteoff);
                }
                #pragma unroll
                for (int ct = 0; ct < 2; ++ct)
                    bb[ct] = *(const bf16x8*)(tcm + (size_t)(w * 32 + ct * 16 + lr) * H2 + ks * 32 + lg * 8);
                #pragma unroll
                for (int jt = 0; jt < 4; ++jt)
                    #pragma unroll
                    for (int ct = 0; ct < 2; ++ct)
                        acc1[jt][ct] = __builtin_amdgcn_mfma_f32_16x16x32_bf16(a[jt], bb[ct], acc1[jt][ct], 0, 0, 0);
            }
            #pragma unroll
            for (int jt = 0; jt < 4; ++jt)
                #pragma unroll
                for (int ct = 0; ct < 2; ++ct)
                    #pragma unroll
                    for (int r = 0; r < 4; ++r) {
                        int j = jt * 16 + lg * 4 + r;
                        int c = w * 32 + ct * 16 + lr;
                        int byteoff = ((((j << 8) + c)) << 1) ^ ((j & 7) << 4);
                        *(unsigned short*)((char*)WS + byteoff) = f2bf(acc1[jt][ct][r]);
                    }
        }
        __syncthreads();

        {
            f32x4 acc2[4];
            #pragma unroll
            for (int jt = 0; jt < 4; ++jt) acc2[jt] = (f32x4){0.f, 0.f, 0.f, 0.f};

            #pragma unroll
            for (int ks = 0; ks < 8; ++ks) {
                #pragma unroll
                for (int jt = 0; jt < 4; ++jt) {
                    int byteoff = ((((jt * 16 + lr) << 8) + ks * 32 + lg * 8) << 1) ^ swz;
                    bf16x8 wb = *(const bf16x8*)((const char*)WS + byteoff);
                    acc2[jt] = __builtin_amdgcn_mfma_f32_16x16x32_bf16(ha[ks], wb, acc2[jt], 0, 0, 0);
                }
            }
            float* po = predT + (size_t)(k * NCLS + m) * (NENT * NENT);
            #pragma unroll
            for (int jt = 0; jt < 4; ++jt)
                #pragma unroll
                for (int r = 0; r < 4; ++r) {
                    int i = w * 16 + lg * 4 + r;
                    int j = jh * 64 + jt * 16 + lr;
                    po[i * NENT + j] = acc2[jt][r];
                }
        }
        __syncthreads();
    }
}

// ---------------- transpose: predT[km][ij] -> out[ij][km] ----------------
__global__ __launch_bounds__(256)
void transpose_out(const float* __restrict__ predT, float* __restrict__ out)
{
    __shared__ float Ls[160][33];
    const int bid = blockIdx.x;
    const int ij0 = (bid >> 2) * 32;
    const int km0 = (bid & 3) * 160;
    const int t = threadIdx.x;

    #pragma unroll
    for (int q = 0; q < 20; ++q) {
        int r = (t >> 5) + q * 8;
        int c = t & 31;
        Ls[r][c] = predT[(size_t)(km0 + r) * 16384 + ij0 + c];
    }
    __syncthreads();
    for (int idx = t; idx < 32 * 160; idx += 256) {
        int r = idx / 160, c = idx % 160;
        out[(size_t)(ij0 + r) * 640 + km0 + c] = Ls[c][r];
    }
}

extern "C" void kernel_launch(void* const* d_in, const int* in_sizes, int n_in,
                              void* d_out, int out_size, void* d_ws, size_t ws_size,
                              hipStream_t stream)
{
    (void)in_sizes; (void)n_in; (void)out_size; (void)ws_size;
    const float* enc  = (const float*)d_in[0];
    const int*   hidx = (const int*)d_in[1];
    const int*   tidx = (const int*)d_in[2];
    const int*   eidx = (const int*)d_in[3];
    const float* Whf = (const float*)d_in[4];
    const float* bhf = (const float*)d_in[5];
    const float* Whb = (const float*)d_in[6];
    const float* bhb = (const float*)d_in[7];
    const float* Wtf = (const float*)d_in[8];
    const float* btf = (const float*)d_in[9];
    const float* Wtb = (const float*)d_in[10];
    const float* btb = (const float*)d_in[11];
    const float* Wef = (const float*)d_in[12];
    const float* bef = (const float*)d_in[13];
    const float* Web = (const float*)d_in[14];
    const float* beb = (const float*)d_in[15];
    const float* T_he  = (const float*)d_in[16];
    const float* T_te  = (const float*)d_in[17];
    const float* T_cls = (const float*)d_in[18];

    float* out = (float*)d_out;
    char*  ws  = (char*)d_ws;
    unsigned short* poolB  = (unsigned short*)(ws + POOLB_OFF);
    unsigned short* hepN   = (unsigned short*)(ws + HEPB_OFF);
    unsigned short* tepN   = (unsigned short*)(ws + TEPB_OFF);
    unsigned short* TclsB  = (unsigned short*)(ws + TCLSB_OFF);
    unsigned short* WB     = (unsigned short*)(ws + WB_OFF);
    unsigned short* tokB   = (unsigned short*)(ws + TOKB_OFF);
    unsigned short* TB     = (unsigned short*)(ws + TB_OFF);
    unsigned short* gatesB = (unsigned short*)(ws + GATESB_OFF);
    float*          predT  = (float*)(ws + PREDT_OFF);

    unsigned short* HeB = poolB;
    unsigned short* TeB = poolB + 1 * NENT * H2;
    unsigned short* EeB = poolB + 2 * NENT * H2;

    prep_kernel<<<7616, 256, 0, stream>>>(Whf, Whb, Wtf, Wtb, Wef, Web,
                                          T_cls, enc, hidx, tidx, eidx,
                                          WB, TclsB, tokB);

    gates_mfma<<<288, 256, 0, stream>>>(tokB, WB, gatesB);

    poolconv<<<896, 256, 0, stream>>>(gatesB, bhf, bhb, btf, btb, bef, beb,
                                      poolB, T_he, TB);

    pairc_mfma<<<512, 1024, 0, stream>>>(EeB, HeB, TeB, TB, T_te, hepN, tepN);

    step3_mfma<<<256, 512, 0, stream>>>(hepN, tepN, TclsB, predT);

    transpose_out<<<2048, 256, 0, stream>>>(predT, out);
}